// Round 1
// baseline (9079.192 us; speedup 1.0000x reference)
//
#include <hip/hip_runtime.h>
#include <math.h>

// Seq2SeqGRU: B=256, IN_LEN=512, H=512, OUT_LEN=10
// Round 1: correctness-first. Per-timestep fused kernel (layer0 step s +
// layer1 step s-1 in one grid), fp16 MFMA 16x16x32 with fp32 gate math.
// 16 row-groups (M=16) x 8 hid-slices (64 dims) per layer = 256 WGs.

#define Hdim 512
#define Gdim 1536
#define Bsz  256
#define Tlen 512
#define OUTL 10

typedef _Float16 half8 __attribute__((ext_vector_type(8)));
typedef float    f32x4 __attribute__((ext_vector_type(4)));

__device__ __forceinline__ f32x4 mfma16(half8 a, half8 b, f32x4 c) {
    return __builtin_amdgcn_mfma_f32_16x16x32_f16(a, b, c, 0, 0, 0);
}

__device__ __forceinline__ float sigmoidf_(float x) {
    return 1.0f / (1.0f + __expf(-x));
}

// One GRU cell step for a 16-row x 64-hid tile.
// MODE 0: gi from x (enc layer0, K=2, fp32)
// MODE 1: gi via fp16 GEMM vs a_gi (enc layer1 / dec layer1)
// MODE 2: gi from per-row scalar (dec layer0, K=1, fp32)
template <int MODE>
__device__ __forceinline__ void gru_half(
    int bid, int t,
    const float* __restrict__ h_in_f32, const _Float16* __restrict__ h_in_f16,
    float* __restrict__ h_out_f32, _Float16* __restrict__ h_out_f16,
    const _Float16* __restrict__ w_hh, const float* __restrict__ b_hh,
    const float* __restrict__ b_ih,
    const float* __restrict__ x,            // MODE 0
    const float* __restrict__ w_ih_f32,     // MODE 0 (1536x2) / MODE 2 (1536x1)
    const _Float16* __restrict__ a_gi,      // MODE 1
    const _Float16* __restrict__ w_ih_f16,  // MODE 1
    const float* __restrict__ scalin)       // MODE 2
{
    const int tid  = threadIdx.x;
    const int wave = tid >> 6;
    const int lane = tid & 63;
    const int rg   = bid >> 3;                   // row group 0..15
    const int cg   = bid & 7;                    // hid slice 0..7
    const int brow = rg * 16;
    const int hidbase = cg * 64 + wave * 16;
    const int cv   = lane & 15;                  // tile col / A row
    const int koff = (lane >> 4) * 8;            // k offset within 32-K tile

    // ---- recurrent GEMM: gh = h @ w_hh.T (3 gate tiles) ----
    const _Float16* ap = h_in_f16 + (size_t)(brow + cv) * Hdim + koff;
    const _Float16* wr = w_hh + (size_t)(      hidbase + cv) * Hdim + koff;
    const _Float16* wz = w_hh + (size_t)( 512 + hidbase + cv) * Hdim + koff;
    const _Float16* wn = w_hh + (size_t)(1024 + hidbase + cv) * Hdim + koff;

    f32x4 ar = {0,0,0,0}, az = {0,0,0,0}, an = {0,0,0,0};
    f32x4 ir = {0,0,0,0}, iz = {0,0,0,0}, in_ = {0,0,0,0};

    const _Float16* ap2 = nullptr;
    const _Float16* wr2 = nullptr; const _Float16* wz2 = nullptr; const _Float16* wn2 = nullptr;
    if (MODE == 1) {
        ap2 = a_gi + (size_t)(brow + cv) * Hdim + koff;
        wr2 = w_ih_f16 + (size_t)(      hidbase + cv) * Hdim + koff;
        wz2 = w_ih_f16 + (size_t)( 512 + hidbase + cv) * Hdim + koff;
        wn2 = w_ih_f16 + (size_t)(1024 + hidbase + cv) * Hdim + koff;
    }

    #pragma unroll 4
    for (int kk = 0; kk < 16; ++kk) {
        half8 a = *(const half8*)(ap + kk * 32);
        ar = mfma16(a, *(const half8*)(wr + kk * 32), ar);
        az = mfma16(a, *(const half8*)(wz + kk * 32), az);
        an = mfma16(a, *(const half8*)(wn + kk * 32), an);
        if (MODE == 1) {
            half8 a2 = *(const half8*)(ap2 + kk * 32);
            ir  = mfma16(a2, *(const half8*)(wr2 + kk * 32), ir);
            iz  = mfma16(a2, *(const half8*)(wz2 + kk * 32), iz);
            in_ = mfma16(a2, *(const half8*)(wn2 + kk * 32), in_);
        }
    }

    // ---- epilogue: gates in fp32 ----
    // C/D layout (m89-verified): col = lane&15, row = (lane>>4)*4 + reg
    const int hid = hidbase + cv;
    const float bhr = b_hh[hid], bhz = b_hh[512 + hid], bhn = b_hh[1024 + hid];
    const float bir = b_ih[hid], biz = b_ih[512 + hid], bin = b_ih[1024 + hid];

    float w0r = 0, w1r = 0, w0z = 0, w1z = 0, w0n = 0, w1n = 0;
    if (MODE == 0) {
        w0r = w_ih_f32[hid * 2];          w1r = w_ih_f32[hid * 2 + 1];
        w0z = w_ih_f32[(512 + hid) * 2];  w1z = w_ih_f32[(512 + hid) * 2 + 1];
        w0n = w_ih_f32[(1024 + hid) * 2]; w1n = w_ih_f32[(1024 + hid) * 2 + 1];
    }
    if (MODE == 2) {
        w0r = w_ih_f32[hid]; w0z = w_ih_f32[512 + hid]; w0n = w_ih_f32[1024 + hid];
    }

    const int rbase = brow + ((lane >> 4) << 2);
    #pragma unroll
    for (int jj = 0; jj < 4; ++jj) {
        const int b = rbase + jj;
        float gr, gz, gn;
        if (MODE == 0) {
            float x0 = x[((size_t)b * Tlen + t) * 2];
            float x1 = x[((size_t)b * Tlen + t) * 2 + 1];
            gr = x0 * w0r + x1 * w1r + bir;
            gz = x0 * w0z + x1 * w1z + biz;
            gn = x0 * w0n + x1 * w1n + bin;
        } else if (MODE == 1) {
            gr = ir[jj] + bir; gz = iz[jj] + biz; gn = in_[jj] + bin;
        } else {
            float d = scalin[b];
            gr = d * w0r + bir; gz = d * w0z + biz; gn = d * w0n + bin;
        }
        float r = sigmoidf_(gr + ar[jj] + bhr);
        float z = sigmoidf_(gz + az[jj] + bhz);
        float n = tanhf(gn + r * (an[jj] + bhn));
        float hold = h_in_f32[(size_t)b * Hdim + hid];
        float hn = (1.0f - z) * n + z * hold;
        h_out_f32[(size_t)b * Hdim + hid] = hn;
        h_out_f16[(size_t)b * Hdim + hid] = (_Float16)hn;
    }
}

// Fused encoder step: blocks [0,128) do layer0 step s; [128,256) do layer1 step s-1.
__global__ __launch_bounds__(256) void enc_step_kernel(
    int s,
    const float* h0i32, const _Float16* h0i16, float* h0o32, _Float16* h0o16,
    const _Float16* whh0, const float* bhh0, const float* bih0,
    const float* x, const float* wih0,
    const float* h1i32, const _Float16* h1i16, float* h1o32, _Float16* h1o16,
    const _Float16* whh1, const float* bhh1, const float* bih1,
    const _Float16* y0, const _Float16* wih1f16)
{
    int bid = blockIdx.x;
    if (bid < 128) {
        if (s >= Tlen) return;
        gru_half<0>(bid, s, h0i32, h0i16, h0o32, h0o16, whh0, bhh0, bih0,
                    x, wih0, nullptr, nullptr, nullptr);
    } else {
        if (s == 0) return;
        gru_half<1>(bid - 128, 0, h1i32, h1i16, h1o32, h1o16, whh1, bhh1, bih1,
                    nullptr, nullptr, y0, wih1f16, nullptr);
    }
}

__global__ __launch_bounds__(256) void dec0_kernel(
    const float* hi32, const _Float16* hi16, float* ho32, _Float16* ho16,
    const _Float16* whh, const float* bhh, const float* bih,
    const float* wih, const float* scalin)
{
    gru_half<2>(blockIdx.x, 0, hi32, hi16, ho32, ho16, whh, bhh, bih,
                nullptr, wih, nullptr, nullptr, scalin);
}

__global__ __launch_bounds__(256) void dec1_kernel(
    const float* hi32, const _Float16* hi16, float* ho32, _Float16* ho16,
    const _Float16* whh, const float* bhh, const float* bih,
    const _Float16* agi, const _Float16* wihf16)
{
    gru_half<1>(blockIdx.x, 0, hi32, hi16, ho32, ho16, whh, bhh, bih,
                nullptr, nullptr, agi, wihf16, nullptr);
}

__global__ void cvt_kernel(const float* __restrict__ src, _Float16* __restrict__ dst, int n) {
    int i = blockIdx.x * blockDim.x + threadIdx.x;
    for (; i < n; i += gridDim.x * blockDim.x) dst[i] = (_Float16)src[i];
}

// LayerNorm of both final hidden states (one wave per row), writes fp32 + fp16.
__global__ __launch_bounds__(64) void ln_kernel(
    float* h0, _Float16* h0f16, float* h1, _Float16* h1f16,
    const float* __restrict__ gamma, const float* __restrict__ beta)
{
    int row = blockIdx.x;            // 0..511
    int b = row & 255;
    float* hp; _Float16* hp16;
    if (row < 256) { hp = h0 + (size_t)b * Hdim; hp16 = h0f16 + (size_t)b * Hdim; }
    else           { hp = h1 + (size_t)b * Hdim; hp16 = h1f16 + (size_t)b * Hdim; }
    int lane = threadIdx.x;
    float4 v0 = *(const float4*)(hp + lane * 8);
    float4 v1 = *(const float4*)(hp + lane * 8 + 4);
    float s  = v0.x + v0.y + v0.z + v0.w + v1.x + v1.y + v1.z + v1.w;
    float sq = v0.x*v0.x + v0.y*v0.y + v0.z*v0.z + v0.w*v0.w
             + v1.x*v1.x + v1.y*v1.y + v1.z*v1.z + v1.w*v1.w;
    #pragma unroll
    for (int m = 1; m < 64; m <<= 1) { s += __shfl_xor(s, m); sq += __shfl_xor(sq, m); }
    float mean = s * (1.0f / 512.0f);
    float var  = sq * (1.0f / 512.0f) - mean * mean;
    float rstd = rsqrtf(var + 1e-5f);
    float vv[8] = {v0.x, v0.y, v0.z, v0.w, v1.x, v1.y, v1.z, v1.w};
    #pragma unroll
    for (int e = 0; e < 8; ++e) {
        int k = lane * 8 + e;
        float o = (vv[e] - mean) * rstd * gamma[k] + beta[k];
        hp[k] = o; hp16[k] = (_Float16)o;
    }
}

__global__ __launch_bounds__(64) void y_kernel(
    const float* __restrict__ h1, const float* __restrict__ fcw,
    const float* __restrict__ fcb, float* __restrict__ ybuf,
    float* __restrict__ out, int t)
{
    int b = blockIdx.x * 64 + threadIdx.x;   // grid 4 -> 256 rows
    const float* hp = h1 + (size_t)b * Hdim;
    float acc = 0.0f;
    #pragma unroll 8
    for (int k = 0; k < Hdim; ++k) acc += hp[k] * fcw[k];
    float y = acc + fcb[0];
    ybuf[b] = y;
    out[(size_t)b * OUTL + t] = y;
}

__global__ void decin_kernel(const float* __restrict__ x, float* __restrict__ ybuf) {
    int b = blockIdx.x * blockDim.x + threadIdx.x;
    if (b < Bsz) ybuf[b] = x[((size_t)b * Tlen + (Tlen - 1)) * 2 + 1];
}

extern "C" void kernel_launch(void* const* d_in, const int* in_sizes, int n_in,
                              void* d_out, int out_size, void* d_ws, size_t ws_size,
                              hipStream_t stream)
{
    const float* x     = (const float*)d_in[0];
    const float* ewih0 = (const float*)d_in[1];
    const float* ewhh0 = (const float*)d_in[2];
    const float* ebih0 = (const float*)d_in[3];
    const float* ebhh0 = (const float*)d_in[4];
    const float* ewih1 = (const float*)d_in[5];
    const float* ewhh1 = (const float*)d_in[6];
    const float* ebih1 = (const float*)d_in[7];
    const float* ebhh1 = (const float*)d_in[8];
    const float* lng   = (const float*)d_in[9];
    const float* lnb   = (const float*)d_in[10];
    const float* dwih0 = (const float*)d_in[11];
    const float* dwhh0 = (const float*)d_in[12];
    const float* dbih0 = (const float*)d_in[13];
    const float* dbhh0 = (const float*)d_in[14];
    const float* dwih1 = (const float*)d_in[15];
    const float* dwhh1 = (const float*)d_in[16];
    const float* dbih1 = (const float*)d_in[17];
    const float* dbhh1 = (const float*)d_in[18];
    const float* fcw   = (const float*)d_in[19];
    const float* fcb   = (const float*)d_in[20];
    float* out = (float*)d_out;

    char* ws = (char*)d_ws;
    size_t off = 0;
    auto alloc = [&](size_t bytes) -> void* {
        void* p = ws + off;
        off += (bytes + 255) & ~(size_t)255;
        return p;
    };

    const size_t HB = (size_t)Bsz * Hdim;     // 131072 elems
    float*    h0f32[2]; float* h1f32[2];
    _Float16* h0f16[2]; _Float16* h1f16[2];
    h0f32[0] = (float*)alloc(HB * 4); h0f32[1] = (float*)alloc(HB * 4);
    h1f32[0] = (float*)alloc(HB * 4); h1f32[1] = (float*)alloc(HB * 4);
    h0f16[0] = (_Float16*)alloc(HB * 2); h0f16[1] = (_Float16*)alloc(HB * 2);
    h1f16[0] = (_Float16*)alloc(HB * 2); h1f16[1] = (_Float16*)alloc(HB * 2);
    size_t hbytes = off;                      // zero all h buffers each call

    const size_t WN = (size_t)Gdim * Hdim;    // 786432 elems per big weight
    _Float16* whh0_16 = (_Float16*)alloc(WN * 2);
    _Float16* wih1_16 = (_Float16*)alloc(WN * 2);
    _Float16* whh1_16 = (_Float16*)alloc(WN * 2);
    _Float16* dwhh0_16 = (_Float16*)alloc(WN * 2);
    _Float16* dwih1_16 = (_Float16*)alloc(WN * 2);
    _Float16* dwhh1_16 = (_Float16*)alloc(WN * 2);
    float* ybuf = (float*)alloc(Bsz * 4);
    (void)ws_size; (void)in_sizes; (void)n_in; (void)out_size;

    hipMemsetAsync(d_ws, 0, hbytes, stream);

    cvt_kernel<<<768, 256, 0, stream>>>(ewhh0, whh0_16, (int)WN);
    cvt_kernel<<<768, 256, 0, stream>>>(ewih1, wih1_16, (int)WN);
    cvt_kernel<<<768, 256, 0, stream>>>(ewhh1, whh1_16, (int)WN);
    cvt_kernel<<<768, 256, 0, stream>>>(dwhh0, dwhh0_16, (int)WN);
    cvt_kernel<<<768, 256, 0, stream>>>(dwih1, dwih1_16, (int)WN);
    cvt_kernel<<<768, 256, 0, stream>>>(dwhh1, dwhh1_16, (int)WN);

    // Encoder: 513 fused launches. Layer0 runs s=0..511, layer1 runs u=s-1=0..511.
    for (int s = 0; s <= Tlen; ++s) {
        int pi  = s & 1, po = pi ^ 1;         // layer0 parity
        int p1i = (s - 1) & 1;                // layer1 parity (s=0 unused)
        int p1o = p1i ^ 1;
        enc_step_kernel<<<256, 256, 0, stream>>>(
            s,
            h0f32[pi], h0f16[pi], h0f32[po], h0f16[po],
            whh0_16, ebhh0, ebih0, x, ewih0,
            h1f32[p1i], h1f16[p1i], h1f32[p1o], h1f16[p1o],
            whh1_16, ebhh1, ebih1,
            /*y0 = layer0 output at step s-1*/ h0f16[s & 1], wih1_16);
    }

    // hT0 in h0f32[0], hT1 in h1f32[0]. LayerNorm both in place (+f16 copies).
    ln_kernel<<<512, 64, 0, stream>>>(h0f32[0], h0f16[0], h1f32[0], h1f16[0], lng, lnb);
    decin_kernel<<<1, 256, 0, stream>>>(x, ybuf);

    // Decoder: 10 steps of (layer0, layer1, fc-out).
    for (int t = 0; t < OUTL; ++t) {
        int pi = t & 1, po = pi ^ 1;
        dec0_kernel<<<128, 256, 0, stream>>>(
            h0f32[pi], h0f16[pi], h0f32[po], h0f16[po],
            dwhh0_16, dbhh0, dbih0, dwih0, ybuf);
        dec1_kernel<<<128, 256, 0, stream>>>(
            h1f32[pi], h1f16[pi], h1f32[po], h1f16[po],
            dwhh1_16, dbhh1, dbih1, /*gi A = dec layer0 output*/ h0f16[po], dwih1_16);
        y_kernel<<<4, 64, 0, stream>>>(h1f32[po], fcw, fcb, ybuf, out, t);
    }
}